// Round 3
// baseline (226.576 us; speedup 1.0000x reference)
//
#include <hip/hip_runtime.h>
#include <hip/hip_bf16.h>

// GraphPosteriorHead: B=32, N=64, D=256
// Pipeline:
//  K0: ctx projections (6x (32,256))       -> ws
//  K1: fused encoders + fi/fj projections  -> fi_dep, fjt_dep, fi_cep, fjt_cep
//      (512 thr, 8 waves, k-split-8 per GEMM stage, LDS partial reduction)
//  K3: edge logits (fused, no h tensor) + entropy partials -> Wd, Wc, entp
//      (256 thr = 4 waves, d-split-4, LDS reduce; full occupancy)
//  K6: gate + combine + W_posterior + expm(trace) per batch -> out, traces
//  K7: acyc reduction -> out[131072]

#define LDS_STRIDE 260   // 256 + 4 pad

__device__ __forceinline__ float gelu_f(float x) {
    return 0.5f * x * (1.0f + erff(x * 0.70710678118654752440f));
}
__device__ __forceinline__ float sigmoid_f(float x) {
    return 1.0f / (1.0f + expf(-x));
}
__device__ __forceinline__ float f4c(const float4& v, int k) {
    return k == 0 ? v.x : k == 1 ? v.y : k == 2 ? v.z : v.w;
}

// ---------------- K0: context projections ----------------
__global__ __launch_bounds__(256) void k0_ctx(
    const float* __restrict__ ds, const float* __restrict__ cc,
    const float* __restrict__ dge_w1, const float* __restrict__ dge_b1,
    const float* __restrict__ cge_w1, const float* __restrict__ cge_b1,
    const float* __restrict__ dep_w1, const float* __restrict__ dep_b1,
    const float* __restrict__ cep_w1, const float* __restrict__ cep_b1,
    float* __restrict__ ctxproj)
{
    const int b = blockIdx.x;
    const int which = blockIdx.y;
    const float* ctx; const float* W; const float* bias;
    switch (which) {
        case 0:  ctx = ds; W = dge_w1 + 256 * 256; bias = dge_b1; break;
        case 1:  ctx = cc; W = cge_w1 + 256 * 256; bias = cge_b1; break;
        case 2:  ctx = ds; W = dep_w1 + 256 * 256; bias = dep_b1; break;
        case 3:  ctx = ds; W = dep_w1 + 768 * 256; bias = nullptr; break;
        case 4:  ctx = cc; W = cep_w1 + 256 * 256; bias = cep_b1; break;
        default: ctx = cc; W = cep_w1 + 768 * 256; bias = nullptr; break;
    }
    __shared__ float sctx[256];
    const int tid = threadIdx.x;
    sctx[tid] = ctx[b * 256 + tid];
    __syncthreads();
    float acc = 0.0f;
    #pragma unroll 2
    for (int k = 0; k < 256; k += 4) {
        float4 c4 = *(const float4*)&sctx[k];
        acc = fmaf(c4.x, W[(k + 0) * 256 + tid], acc);
        acc = fmaf(c4.y, W[(k + 1) * 256 + tid], acc);
        acc = fmaf(c4.z, W[(k + 2) * 256 + tid], acc);
        acc = fmaf(c4.w, W[(k + 3) * 256 + tid], acc);
    }
    if (bias) acc += bias[tid];
    ctxproj[(which * 32 + b) * 256 + tid] = acc;
}

// ---------------- K1: fused encoders, k-split across 8 waves ----------------
__device__ __forceinline__ void gemm_ks(const float* __restrict__ src,  // LDS [8][LDS_STRIDE]
                                        const float* __restrict__ W,    // global [256][256]
                                        int ks0, int t0, float acc[8][4])
{
    #pragma unroll
    for (int r = 0; r < 8; ++r)
        #pragma unroll
        for (int c = 0; c < 4; ++c) acc[r][c] = 0.0f;
    #pragma unroll 2
    for (int k = ks0; k < ks0 + 32; k += 4) {
        float4 wv0 = *(const float4*)&W[(k + 0) * 256 + t0];
        float4 wv1 = *(const float4*)&W[(k + 1) * 256 + t0];
        float4 wv2 = *(const float4*)&W[(k + 2) * 256 + t0];
        float4 wv3 = *(const float4*)&W[(k + 3) * 256 + t0];
        float4 a[8];
        #pragma unroll
        for (int r = 0; r < 8; ++r) a[r] = *(const float4*)&src[r * LDS_STRIDE + k];
        float4 wvs[4] = {wv0, wv1, wv2, wv3};
        #pragma unroll
        for (int kk = 0; kk < 4; ++kk) {
            float4 wv = wvs[kk];
            #pragma unroll
            for (int r = 0; r < 8; ++r) {
                float av = f4c(a[r], kk);
                acc[r][0] = fmaf(av, wv.x, acc[r][0]);
                acc[r][1] = fmaf(av, wv.y, acc[r][1]);
                acc[r][2] = fmaf(av, wv.z, acc[r][2]);
                acc[r][3] = fmaf(av, wv.w, acc[r][3]);
            }
        }
    }
}

__device__ __forceinline__ void write_part(float* __restrict__ part, int w, int t0,
                                           const float acc[8][4])
{
    #pragma unroll
    for (int r = 0; r < 8; ++r) {
        float4 o = {acc[r][0], acc[r][1], acc[r][2], acc[r][3]};
        *(float4*)&part[(w * 8 + r) * 256 + t0] = o;
    }
}

__device__ __forceinline__ float4 reduce_part(const float* __restrict__ part, int r, int t0)
{
    float4 s = {0.0f, 0.0f, 0.0f, 0.0f};
    #pragma unroll
    for (int w = 0; w < 8; ++w) {
        float4 v = *(const float4*)&part[(w * 8 + r) * 256 + t0];
        s.x += v.x; s.y += v.y; s.z += v.z; s.w += v.w;
    }
    return s;
}

__global__ __launch_bounds__(512) void k1_encode(
    const float* __restrict__ ve_g,
    const float* __restrict__ dge_w1, const float* __restrict__ dge_w2, const float* __restrict__ dge_b2,
    const float* __restrict__ cge_w1, const float* __restrict__ cge_w2, const float* __restrict__ cge_b2,
    const float* __restrict__ dep_w1, const float* __restrict__ cep_w1,
    const float* __restrict__ ctxproj,
    float* __restrict__ fi_dep, float* __restrict__ fjt_dep,
    float* __restrict__ fi_cep, float* __restrict__ fjt_cep)
{
    __shared__ float sve[8 * LDS_STRIDE];
    __shared__ float sA[8 * LDS_STRIDE];
    __shared__ float sB[8 * LDS_STRIDE];
    __shared__ float part[8 * 8 * 256];   // 64 KB partials

    const int tid = threadIdx.x;
    const int b = blockIdx.x >> 3;
    const int chunk = blockIdx.x & 7;
    const int n0 = chunk * 8;

    const int w  = tid >> 6;          // wave id 0..7
    const int t0 = (tid & 63) * 4;    // 4-col slice
    const int ks0 = w * 32;           // k-slice

    {
        int idx = tid * 4;
        int r = idx >> 8, k = idx & 255;
        *(float4*)&sve[r * LDS_STRIDE + k] = *(const float4*)&ve_g[(b * 64 + n0) * 256 + idx];
    }
    __syncthreads();

    float acc[8][4];

    // ---- 1. dge stage1: sve -> sA
    gemm_ks(sve, dge_w1, ks0, t0, acc);
    write_part(part, w, t0, acc);
    __syncthreads();
    {
        float4 s = reduce_part(part, w, t0);
        float4 cp = *(const float4*)&ctxproj[(0 * 32 + b) * 256 + t0];
        float4 o = {gelu_f(s.x + cp.x), gelu_f(s.y + cp.y), gelu_f(s.z + cp.z), gelu_f(s.w + cp.w)};
        *(float4*)&sA[w * LDS_STRIDE + t0] = o;
    }
    __syncthreads();

    // ---- 2. dge stage2: sA -> sB (var_data)
    gemm_ks(sA, dge_w2, ks0, t0, acc);
    write_part(part, w, t0, acc);
    __syncthreads();
    {
        float4 s = reduce_part(part, w, t0);
        float4 bv = *(const float4*)&dge_b2[t0];
        float4 o = {gelu_f(s.x + bv.x), gelu_f(s.y + bv.y), gelu_f(s.z + bv.z), gelu_f(s.w + bv.w)};
        *(float4*)&sB[w * LDS_STRIDE + t0] = o;
    }
    __syncthreads();

    // ---- 3. dep fi: sB -> global
    gemm_ks(sB, dep_w1, ks0, t0, acc);
    write_part(part, w, t0, acc);
    __syncthreads();
    {
        float4 s = reduce_part(part, w, t0);
        float4 cp = *(const float4*)&ctxproj[(2 * 32 + b) * 256 + t0];
        float4 o = {s.x + cp.x, s.y + cp.y, s.z + cp.z, s.w + cp.w};
        *(float4*)&fi_dep[(b * 64 + n0 + w) * 256 + t0] = o;
    }
    __syncthreads();

    // ---- 4. dep fj: sB -> sA, then transpose to fjt_dep
    gemm_ks(sB, dep_w1 + 512 * 256, ks0, t0, acc);
    write_part(part, w, t0, acc);
    __syncthreads();
    {
        float4 s = reduce_part(part, w, t0);
        float4 cp = *(const float4*)&ctxproj[(3 * 32 + b) * 256 + t0];
        float4 o = {s.x + cp.x, s.y + cp.y, s.z + cp.z, s.w + cp.w};
        *(float4*)&sA[w * LDS_STRIDE + t0] = o;
    }
    __syncthreads();
    {
        int t = tid & 255, half = tid >> 8;
        float v0 = sA[(half * 4 + 0) * LDS_STRIDE + t];
        float v1 = sA[(half * 4 + 1) * LDS_STRIDE + t];
        float v2 = sA[(half * 4 + 2) * LDS_STRIDE + t];
        float v3 = sA[(half * 4 + 3) * LDS_STRIDE + t];
        float4 o = {v0, v1, v2, v3};
        *(float4*)&fjt_dep[(b * 256 + t) * 64 + n0 + half * 4] = o;
    }

    // ---- 5. cge stage1: sve -> sB
    gemm_ks(sve, cge_w1, ks0, t0, acc);
    write_part(part, w, t0, acc);
    __syncthreads();
    {
        float4 s = reduce_part(part, w, t0);
        float4 cp = *(const float4*)&ctxproj[(1 * 32 + b) * 256 + t0];
        float4 o = {gelu_f(s.x + cp.x), gelu_f(s.y + cp.y), gelu_f(s.z + cp.z), gelu_f(s.w + cp.w)};
        *(float4*)&sB[w * LDS_STRIDE + t0] = o;
    }
    __syncthreads();

    // ---- 6. cge stage2: sB -> sA (var_claim)
    gemm_ks(sB, cge_w2, ks0, t0, acc);
    write_part(part, w, t0, acc);
    __syncthreads();
    {
        float4 s = reduce_part(part, w, t0);
        float4 bv = *(const float4*)&cge_b2[t0];
        float4 o = {gelu_f(s.x + bv.x), gelu_f(s.y + bv.y), gelu_f(s.z + bv.z), gelu_f(s.w + bv.w)};
        *(float4*)&sA[w * LDS_STRIDE + t0] = o;
    }
    __syncthreads();

    // ---- 7. cep fi: sA -> global
    gemm_ks(sA, cep_w1, ks0, t0, acc);
    write_part(part, w, t0, acc);
    __syncthreads();
    {
        float4 s = reduce_part(part, w, t0);
        float4 cp = *(const float4*)&ctxproj[(4 * 32 + b) * 256 + t0];
        float4 o = {s.x + cp.x, s.y + cp.y, s.z + cp.z, s.w + cp.w};
        *(float4*)&fi_cep[(b * 64 + n0 + w) * 256 + t0] = o;
    }
    __syncthreads();

    // ---- 8. cep fj: sA -> sB, then transpose to fjt_cep
    gemm_ks(sA, cep_w1 + 512 * 256, ks0, t0, acc);
    write_part(part, w, t0, acc);
    __syncthreads();
    {
        float4 s = reduce_part(part, w, t0);
        float4 cp = *(const float4*)&ctxproj[(5 * 32 + b) * 256 + t0];
        float4 o = {s.x + cp.x, s.y + cp.y, s.z + cp.z, s.w + cp.w};
        *(float4*)&sB[w * LDS_STRIDE + t0] = o;
    }
    __syncthreads();
    {
        int t = tid & 255, half = tid >> 8;
        float v0 = sB[(half * 4 + 0) * LDS_STRIDE + t];
        float v1 = sB[(half * 4 + 1) * LDS_STRIDE + t];
        float v2 = sB[(half * 4 + 2) * LDS_STRIDE + t];
        float v3 = sB[(half * 4 + 3) * LDS_STRIDE + t];
        float4 o = {v0, v1, v2, v3};
        *(float4*)&fjt_cep[(b * 256 + t) * 64 + n0 + half * 4] = o;
    }
}

// ---------------- K3: fused edge logits + entropy, d-split 4 waves ----------------
// grid 2048 = (b,i); block 256: wave s=tid>>6 covers d in [64s,64s+64), lane j=tid&63.
__global__ __launch_bounds__(256) void k3_edges(
    const float* __restrict__ fi_dep, const float* __restrict__ fjt_dep,
    const float* __restrict__ fi_cep, const float* __restrict__ fjt_cep,
    const float* __restrict__ dep_w2, const float* __restrict__ dep_b2,
    const float* __restrict__ cep_w2, const float* __restrict__ cep_b2,
    float* __restrict__ Wd, float* __restrict__ Wc, float* __restrict__ entp)
{
    __shared__ float redD[4][64];
    __shared__ float redC[4][64];

    const int b = blockIdx.x >> 6;
    const int i = blockIdx.x & 63;
    const int s = threadIdx.x >> 6;
    const int j = threadIdx.x & 63;

    const float4* fiD = (const float4*)(fi_dep + (b * 64 + i) * 256) + s * 16;
    const float4* fiC = (const float4*)(fi_cep + (b * 64 + i) * 256) + s * 16;
    const float*  fjD = fjt_dep + (b * 256 + s * 64) * 64 + j;
    const float*  fjC = fjt_cep + (b * 256 + s * 64) * 64 + j;
    const float4* w2D = (const float4*)dep_w2 + s * 16;
    const float4* w2C = (const float4*)cep_w2 + s * 16;

    float accD = 0.0f, accC = 0.0f;
    #pragma unroll 4
    for (int m = 0; m < 16; ++m) {
        float4 fd = fiD[m];
        float4 wd = w2D[m];
        const float* g = fjD + (4 * m) * 64;
        accD = fmaf(gelu_f(fd.x + g[0]),       wd.x, accD);
        accD = fmaf(gelu_f(fd.y + g[64]),      wd.y, accD);
        accD = fmaf(gelu_f(fd.z + g[128]),     wd.z, accD);
        accD = fmaf(gelu_f(fd.w + g[192]),     wd.w, accD);

        float4 fc = fiC[m];
        float4 wc = w2C[m];
        const float* h = fjC + (4 * m) * 64;
        accC = fmaf(gelu_f(fc.x + h[0]),       wc.x, accC);
        accC = fmaf(gelu_f(fc.y + h[64]),      wc.y, accC);
        accC = fmaf(gelu_f(fc.z + h[128]),     wc.z, accC);
        accC = fmaf(gelu_f(fc.w + h[192]),     wc.w, accC);
    }
    redD[s][j] = accD;
    redC[s][j] = accC;
    __syncthreads();

    if (s == 0) {
        float lD = ((redD[0][j] + redD[1][j]) + (redD[2][j] + redD[3][j])) + dep_b2[0];
        float lC = ((redC[0][j] + redC[1][j]) + (redC[2][j] + redC[3][j])) + cep_b2[0];
        if (j == i) { lD = -1e9f; lC = -1e9f; }
        Wd[(b * 64 + i) * 64 + j] = lD;
        Wc[(b * 64 + i) * 64 + j] = lC;

        float p = sigmoid_f(lD);
        float e = -(p * logf(p + 1e-8f) + (1.0f - p) * logf(1.0f - p + 1e-8f));
        #pragma unroll
        for (int off = 32; off; off >>= 1) e += __shfl_down(e, off);
        if (j == 0) entp[b * 64 + i] = e;
    }
}

// ---------------- K6: gate + combine + expm ----------------
__global__ __launch_bounds__(256) void k6_gate_expm(
    const float* __restrict__ Wd, const float* __restrict__ Wc,
    const float* __restrict__ entp,
    const float* __restrict__ gw1, const float* __restrict__ gb1,
    const float* __restrict__ gw2, const float* __restrict__ gb2,
    const int* __restrict__ n_samples,
    float* __restrict__ out, float* __restrict__ traces)
{
    __shared__ float Xs[64 * 68];
    __shared__ float Rs[64 * 68];
    __shared__ float sgate;
    __shared__ float sent;
    __shared__ int ssexp;

    const int b = blockIdx.x;
    const int tid = threadIdx.x;

    if (tid == 0) {
        float s = 0.0f;
        for (int c = 0; c < 64; ++c) s += entp[b * 64 + c];
        sent = s / 4096.0f;
    }
    __syncthreads();
    if (tid < 64) {
        float ns = fminf((float)n_samples[0] / 1000.0f, 1.0f);
        float ccf = 0.5f;
        float pre = ns * gw1[tid] + ccf * gw1[64 + tid] + sent * gw1[128 + tid] + gb1[tid];
        float hid = gelu_f(pre) * gw2[tid];
        #pragma unroll
        for (int off = 32; off; off >>= 1) hid += __shfl_down(hid, off);
        if (tid == 0) sgate = sigmoid_f(hid + gb2[0]);
    }
    __syncthreads();
    const float g = sgate;

    for (int idx = tid; idx < 4096; idx += 256) {
        float d = Wd[b * 4096 + idx];
        float c = Wc[b * 4096 + idx];
        float post = g * d + (1.0f - g) * c;
        float s = sigmoid_f(post);
        out[b * 4096 + idx] = s;
        int ii = idx >> 6, jj = idx & 63;
        Xs[ii * 68 + jj] = s * s;
    }
    __syncthreads();

    if (tid < 64) {
        float cs = 0.0f;
        for (int r = 0; r < 64; ++r) cs += Xs[r * 68 + tid];
        #pragma unroll
        for (int off = 32; off; off >>= 1) cs = fmaxf(cs, __shfl_down(cs, off));
        if (tid == 0) {
            int se = 0;
            if (cs > 0.5f) se = (int)ceilf(log2f(cs * 2.0f));
            if (se < 0) se = 0;
            if (se > 12) se = 12;
            ssexp = se;
        }
    }
    __syncthreads();
    const int sexp = ssexp;
    const float scale = ldexpf(1.0f, -sexp);
    for (int idx = tid; idx < 4096; idx += 256) {
        Xs[(idx >> 6) * 68 + (idx & 63)] *= scale;
    }
    __syncthreads();

    for (int idx = tid; idx < 4096; idx += 256) {
        int ii = idx >> 6, jj = idx & 63;
        Rs[ii * 68 + jj] = Xs[ii * 68 + jj] * (1.0f / 14.0f) + ((ii == jj) ? 1.0f : 0.0f);
    }
    __syncthreads();

    const int rq = tid >> 4, cq = tid & 15;
    const int r0 = rq * 4, c0 = cq * 4;

    for (int k = 13; k >= 1; --k) {
        float acc[4][4];
        #pragma unroll
        for (int i = 0; i < 4; ++i)
            #pragma unroll
            for (int j = 0; j < 4; ++j) acc[i][j] = 0.0f;
        for (int kb = 0; kb < 64; kb += 4) {
            float4 xa[4];
            #pragma unroll
            for (int i = 0; i < 4; ++i) xa[i] = *(const float4*)&Xs[(r0 + i) * 68 + kb];
            #pragma unroll
            for (int kk = 0; kk < 4; ++kk) {
                float4 rv = *(const float4*)&Rs[(kb + kk) * 68 + c0];
                float rj[4] = {rv.x, rv.y, rv.z, rv.w};
                #pragma unroll
                for (int i = 0; i < 4; ++i) {
                    float xv = f4c(xa[i], kk);
                    #pragma unroll
                    for (int j = 0; j < 4; ++j) acc[i][j] = fmaf(xv, rj[j], acc[i][j]);
                }
            }
        }
        __syncthreads();
        float invk = 1.0f / (float)k;
        #pragma unroll
        for (int i = 0; i < 4; ++i)
            #pragma unroll
            for (int j = 0; j < 4; ++j)
                Rs[(r0 + i) * 68 + c0 + j] = acc[i][j] * invk + (((r0 + i) == (c0 + j)) ? 1.0f : 0.0f);
        __syncthreads();
    }

    for (int sq = 0; sq < sexp; ++sq) {
        double acc[4][4];
        #pragma unroll
        for (int i = 0; i < 4; ++i)
            #pragma unroll
            for (int j = 0; j < 4; ++j) acc[i][j] = 0.0;
        for (int kb = 0; kb < 64; kb += 4) {
            float4 xa[4];
            #pragma unroll
            for (int i = 0; i < 4; ++i) xa[i] = *(const float4*)&Rs[(r0 + i) * 68 + kb];
            #pragma unroll
            for (int kk = 0; kk < 4; ++kk) {
                float4 rv = *(const float4*)&Rs[(kb + kk) * 68 + c0];
                double rj[4] = {(double)rv.x, (double)rv.y, (double)rv.z, (double)rv.w};
                #pragma unroll
                for (int i = 0; i < 4; ++i) {
                    double xv = (double)f4c(xa[i], kk);
                    #pragma unroll
                    for (int j = 0; j < 4; ++j) acc[i][j] = fma(xv, rj[j], acc[i][j]);
                }
            }
        }
        __syncthreads();
        #pragma unroll
        for (int i = 0; i < 4; ++i)
            #pragma unroll
            for (int j = 0; j < 4; ++j)
                Rs[(r0 + i) * 68 + c0 + j] = (float)acc[i][j];
        __syncthreads();
    }

    if (tid == 0) {
        double tr = 0.0;
        for (int i = 0; i < 64; ++i) tr += (double)Rs[i * 68 + i];
        traces[b] = (float)tr;
    }
}

// ---------------- K7: acyc ----------------
__global__ void k7_acyc(const float* __restrict__ traces, float* __restrict__ out)
{
    if (threadIdx.x == 0 && blockIdx.x == 0) {
        double s = 0.0;
        for (int b = 0; b < 32; ++b) s += (double)traces[b];
        out[131072] = (float)(s / 32.0 - 64.0);
    }
}

extern "C" void kernel_launch(void* const* d_in, const int* in_sizes, int n_in,
                              void* d_out, int out_size, void* d_ws, size_t ws_size,
                              hipStream_t stream)
{
    (void)in_sizes; (void)n_in; (void)out_size; (void)ws_size;

    const float* ds     = (const float*)d_in[0];
    const float* ve     = (const float*)d_in[1];
    const float* cc     = (const float*)d_in[2];
    const float* dge_w1 = (const float*)d_in[3];
    const float* dge_b1 = (const float*)d_in[4];
    const float* dge_w2 = (const float*)d_in[5];
    const float* dge_b2 = (const float*)d_in[6];
    const float* cge_w1 = (const float*)d_in[7];
    const float* cge_b1 = (const float*)d_in[8];
    const float* cge_w2 = (const float*)d_in[9];
    const float* cge_b2 = (const float*)d_in[10];
    const float* dep_w1 = (const float*)d_in[11];
    const float* dep_b1 = (const float*)d_in[12];
    const float* dep_w2 = (const float*)d_in[13];
    const float* dep_b2 = (const float*)d_in[14];
    const float* cep_w1 = (const float*)d_in[15];
    const float* cep_b1 = (const float*)d_in[16];
    const float* cep_w2 = (const float*)d_in[17];
    const float* cep_b2 = (const float*)d_in[18];
    const float* gw1    = (const float*)d_in[19];
    const float* gb1    = (const float*)d_in[20];
    const float* gw2    = (const float*)d_in[21];
    const float* gb2    = (const float*)d_in[22];
    const int*   nsamp  = (const int*)d_in[23];

    float* ws = (float*)d_ws;
    float* ctxproj = ws;                       // 6*32*256   = 49152
    float* fi_dep  = ctxproj + 49152;          // 32*64*256  = 524288
    float* fjt_dep = fi_dep + 524288;          // 524288
    float* fi_cep  = fjt_dep + 524288;         // 524288
    float* fjt_cep = fi_cep + 524288;          // 524288
    float* Wd      = fjt_cep + 524288;         // 131072
    float* Wc      = Wd + 131072;              // 131072
    float* entp    = Wc + 131072;              // 2048
    float* traces  = entp + 2048;              // 32

    float* outp = (float*)d_out;

    k0_ctx<<<dim3(32, 6), 256, 0, stream>>>(ds, cc, dge_w1, dge_b1, cge_w1, cge_b1,
                                            dep_w1, dep_b1, cep_w1, cep_b1, ctxproj);
    k1_encode<<<256, 512, 0, stream>>>(ve, dge_w1, dge_w2, dge_b2,
                                       cge_w1, cge_w2, cge_b2,
                                       dep_w1, cep_w1, ctxproj,
                                       fi_dep, fjt_dep, fi_cep, fjt_cep);
    k3_edges<<<2048, 256, 0, stream>>>(fi_dep, fjt_dep, fi_cep, fjt_cep,
                                       dep_w2, dep_b2, cep_w2, cep_b2,
                                       Wd, Wc, entp);
    k6_gate_expm<<<32, 256, 0, stream>>>(Wd, Wc, entp, gw1, gb1, gw2, gb2,
                                         nsamp, outp, traces);
    k7_acyc<<<1, 64, 0, stream>>>(traces, outp);
}

// Round 4
// 152.370 us; speedup vs baseline: 1.4870x; 1.4870x over previous
//
#include <hip/hip_runtime.h>
#include <hip/hip_bf16.h>

// GraphPosteriorHead: B=32, N=64, D=256
// Pipeline:
//  K0: ctx projections (6x (32,256))       -> ws
//  K1: fused encoders + fi/fj projections  -> fi_dep, fjt_dep, fi_cep, fjt_cep
//      (512 thr, 8 waves, k-split-8 per GEMM stage, LDS partial reduction)
//  K3: edge logits + entropy; LDS-staged fjt chunks, 4 i-rows/block reuse
//      (512 blocks x 256 thr; wave = one i row; no cross-wave reduction)
//  K6: gate + combine + W_posterior + expm(trace) per batch -> out, traces
//  K7: acyc reduction -> out[131072]

#define LDS_STRIDE 260   // 256 + 4 pad

__device__ __forceinline__ float gelu_f(float x) {
    return 0.5f * x * (1.0f + erff(x * 0.70710678118654752440f));
}
__device__ __forceinline__ float sigmoid_f(float x) {
    return 1.0f / (1.0f + expf(-x));
}
__device__ __forceinline__ float f4c(const float4& v, int k) {
    return k == 0 ? v.x : k == 1 ? v.y : k == 2 ? v.z : v.w;
}

// ---------------- K0: context projections ----------------
__global__ __launch_bounds__(256) void k0_ctx(
    const float* __restrict__ ds, const float* __restrict__ cc,
    const float* __restrict__ dge_w1, const float* __restrict__ dge_b1,
    const float* __restrict__ cge_w1, const float* __restrict__ cge_b1,
    const float* __restrict__ dep_w1, const float* __restrict__ dep_b1,
    const float* __restrict__ cep_w1, const float* __restrict__ cep_b1,
    float* __restrict__ ctxproj)
{
    const int b = blockIdx.x;
    const int which = blockIdx.y;
    const float* ctx; const float* W; const float* bias;
    switch (which) {
        case 0:  ctx = ds; W = dge_w1 + 256 * 256; bias = dge_b1; break;
        case 1:  ctx = cc; W = cge_w1 + 256 * 256; bias = cge_b1; break;
        case 2:  ctx = ds; W = dep_w1 + 256 * 256; bias = dep_b1; break;
        case 3:  ctx = ds; W = dep_w1 + 768 * 256; bias = nullptr; break;
        case 4:  ctx = cc; W = cep_w1 + 256 * 256; bias = cep_b1; break;
        default: ctx = cc; W = cep_w1 + 768 * 256; bias = nullptr; break;
    }
    __shared__ float sctx[256];
    const int tid = threadIdx.x;
    sctx[tid] = ctx[b * 256 + tid];
    __syncthreads();
    float acc = 0.0f;
    #pragma unroll 2
    for (int k = 0; k < 256; k += 4) {
        float4 c4 = *(const float4*)&sctx[k];
        acc = fmaf(c4.x, W[(k + 0) * 256 + tid], acc);
        acc = fmaf(c4.y, W[(k + 1) * 256 + tid], acc);
        acc = fmaf(c4.z, W[(k + 2) * 256 + tid], acc);
        acc = fmaf(c4.w, W[(k + 3) * 256 + tid], acc);
    }
    if (bias) acc += bias[tid];
    ctxproj[(which * 32 + b) * 256 + tid] = acc;
}

// ---------------- K1: fused encoders, k-split across 8 waves ----------------
__device__ __forceinline__ void gemm_ks(const float* __restrict__ src,  // LDS [8][LDS_STRIDE]
                                        const float* __restrict__ W,    // global [256][256]
                                        int ks0, int t0, float acc[8][4])
{
    #pragma unroll
    for (int r = 0; r < 8; ++r)
        #pragma unroll
        for (int c = 0; c < 4; ++c) acc[r][c] = 0.0f;
    #pragma unroll 2
    for (int k = ks0; k < ks0 + 32; k += 4) {
        float4 wv0 = *(const float4*)&W[(k + 0) * 256 + t0];
        float4 wv1 = *(const float4*)&W[(k + 1) * 256 + t0];
        float4 wv2 = *(const float4*)&W[(k + 2) * 256 + t0];
        float4 wv3 = *(const float4*)&W[(k + 3) * 256 + t0];
        float4 a[8];
        #pragma unroll
        for (int r = 0; r < 8; ++r) a[r] = *(const float4*)&src[r * LDS_STRIDE + k];
        float4 wvs[4] = {wv0, wv1, wv2, wv3};
        #pragma unroll
        for (int kk = 0; kk < 4; ++kk) {
            float4 wv = wvs[kk];
            #pragma unroll
            for (int r = 0; r < 8; ++r) {
                float av = f4c(a[r], kk);
                acc[r][0] = fmaf(av, wv.x, acc[r][0]);
                acc[r][1] = fmaf(av, wv.y, acc[r][1]);
                acc[r][2] = fmaf(av, wv.z, acc[r][2]);
                acc[r][3] = fmaf(av, wv.w, acc[r][3]);
            }
        }
    }
}

__device__ __forceinline__ void write_part(float* __restrict__ part, int w, int t0,
                                           const float acc[8][4])
{
    #pragma unroll
    for (int r = 0; r < 8; ++r) {
        float4 o = {acc[r][0], acc[r][1], acc[r][2], acc[r][3]};
        *(float4*)&part[(w * 8 + r) * 256 + t0] = o;
    }
}

__device__ __forceinline__ float4 reduce_part(const float* __restrict__ part, int r, int t0)
{
    float4 s = {0.0f, 0.0f, 0.0f, 0.0f};
    #pragma unroll
    for (int w = 0; w < 8; ++w) {
        float4 v = *(const float4*)&part[(w * 8 + r) * 256 + t0];
        s.x += v.x; s.y += v.y; s.z += v.z; s.w += v.w;
    }
    return s;
}

__global__ __launch_bounds__(512) void k1_encode(
    const float* __restrict__ ve_g,
    const float* __restrict__ dge_w1, const float* __restrict__ dge_w2, const float* __restrict__ dge_b2,
    const float* __restrict__ cge_w1, const float* __restrict__ cge_w2, const float* __restrict__ cge_b2,
    const float* __restrict__ dep_w1, const float* __restrict__ cep_w1,
    const float* __restrict__ ctxproj,
    float* __restrict__ fi_dep, float* __restrict__ fjt_dep,
    float* __restrict__ fi_cep, float* __restrict__ fjt_cep)
{
    __shared__ float sve[8 * LDS_STRIDE];
    __shared__ float sA[8 * LDS_STRIDE];
    __shared__ float sB[8 * LDS_STRIDE];
    __shared__ float part[8 * 8 * 256];   // 64 KB partials

    const int tid = threadIdx.x;
    const int b = blockIdx.x >> 3;
    const int chunk = blockIdx.x & 7;
    const int n0 = chunk * 8;

    const int w  = tid >> 6;          // wave id 0..7
    const int t0 = (tid & 63) * 4;    // 4-col slice
    const int ks0 = w * 32;           // k-slice

    {
        int idx = tid * 4;
        int r = idx >> 8, k = idx & 255;
        *(float4*)&sve[r * LDS_STRIDE + k] = *(const float4*)&ve_g[(b * 64 + n0) * 256 + idx];
    }
    __syncthreads();

    float acc[8][4];

    // ---- 1. dge stage1: sve -> sA
    gemm_ks(sve, dge_w1, ks0, t0, acc);
    write_part(part, w, t0, acc);
    __syncthreads();
    {
        float4 s = reduce_part(part, w, t0);
        float4 cp = *(const float4*)&ctxproj[(0 * 32 + b) * 256 + t0];
        float4 o = {gelu_f(s.x + cp.x), gelu_f(s.y + cp.y), gelu_f(s.z + cp.z), gelu_f(s.w + cp.w)};
        *(float4*)&sA[w * LDS_STRIDE + t0] = o;
    }
    __syncthreads();

    // ---- 2. dge stage2: sA -> sB (var_data)
    gemm_ks(sA, dge_w2, ks0, t0, acc);
    write_part(part, w, t0, acc);
    __syncthreads();
    {
        float4 s = reduce_part(part, w, t0);
        float4 bv = *(const float4*)&dge_b2[t0];
        float4 o = {gelu_f(s.x + bv.x), gelu_f(s.y + bv.y), gelu_f(s.z + bv.z), gelu_f(s.w + bv.w)};
        *(float4*)&sB[w * LDS_STRIDE + t0] = o;
    }
    __syncthreads();

    // ---- 3. dep fi: sB -> global
    gemm_ks(sB, dep_w1, ks0, t0, acc);
    write_part(part, w, t0, acc);
    __syncthreads();
    {
        float4 s = reduce_part(part, w, t0);
        float4 cp = *(const float4*)&ctxproj[(2 * 32 + b) * 256 + t0];
        float4 o = {s.x + cp.x, s.y + cp.y, s.z + cp.z, s.w + cp.w};
        *(float4*)&fi_dep[(b * 64 + n0 + w) * 256 + t0] = o;
    }
    __syncthreads();

    // ---- 4. dep fj: sB -> sA, then transpose to fjt_dep
    gemm_ks(sB, dep_w1 + 512 * 256, ks0, t0, acc);
    write_part(part, w, t0, acc);
    __syncthreads();
    {
        float4 s = reduce_part(part, w, t0);
        float4 cp = *(const float4*)&ctxproj[(3 * 32 + b) * 256 + t0];
        float4 o = {s.x + cp.x, s.y + cp.y, s.z + cp.z, s.w + cp.w};
        *(float4*)&sA[w * LDS_STRIDE + t0] = o;
    }
    __syncthreads();
    {
        int t = tid & 255, half = tid >> 8;
        float v0 = sA[(half * 4 + 0) * LDS_STRIDE + t];
        float v1 = sA[(half * 4 + 1) * LDS_STRIDE + t];
        float v2 = sA[(half * 4 + 2) * LDS_STRIDE + t];
        float v3 = sA[(half * 4 + 3) * LDS_STRIDE + t];
        float4 o = {v0, v1, v2, v3};
        *(float4*)&fjt_dep[(b * 256 + t) * 64 + n0 + half * 4] = o;
    }

    // ---- 5. cge stage1: sve -> sB
    gemm_ks(sve, cge_w1, ks0, t0, acc);
    write_part(part, w, t0, acc);
    __syncthreads();
    {
        float4 s = reduce_part(part, w, t0);
        float4 cp = *(const float4*)&ctxproj[(1 * 32 + b) * 256 + t0];
        float4 o = {gelu_f(s.x + cp.x), gelu_f(s.y + cp.y), gelu_f(s.z + cp.z), gelu_f(s.w + cp.w)};
        *(float4*)&sB[w * LDS_STRIDE + t0] = o;
    }
    __syncthreads();

    // ---- 6. cge stage2: sB -> sA (var_claim)
    gemm_ks(sB, cge_w2, ks0, t0, acc);
    write_part(part, w, t0, acc);
    __syncthreads();
    {
        float4 s = reduce_part(part, w, t0);
        float4 bv = *(const float4*)&cge_b2[t0];
        float4 o = {gelu_f(s.x + bv.x), gelu_f(s.y + bv.y), gelu_f(s.z + bv.z), gelu_f(s.w + bv.w)};
        *(float4*)&sA[w * LDS_STRIDE + t0] = o;
    }
    __syncthreads();

    // ---- 7. cep fi: sA -> global
    gemm_ks(sA, cep_w1, ks0, t0, acc);
    write_part(part, w, t0, acc);
    __syncthreads();
    {
        float4 s = reduce_part(part, w, t0);
        float4 cp = *(const float4*)&ctxproj[(4 * 32 + b) * 256 + t0];
        float4 o = {s.x + cp.x, s.y + cp.y, s.z + cp.z, s.w + cp.w};
        *(float4*)&fi_cep[(b * 64 + n0 + w) * 256 + t0] = o;
    }
    __syncthreads();

    // ---- 8. cep fj: sA -> sB, then transpose to fjt_cep
    gemm_ks(sA, cep_w1 + 512 * 256, ks0, t0, acc);
    write_part(part, w, t0, acc);
    __syncthreads();
    {
        float4 s = reduce_part(part, w, t0);
        float4 cp = *(const float4*)&ctxproj[(5 * 32 + b) * 256 + t0];
        float4 o = {s.x + cp.x, s.y + cp.y, s.z + cp.z, s.w + cp.w};
        *(float4*)&sB[w * LDS_STRIDE + t0] = o;
    }
    __syncthreads();
    {
        int t = tid & 255, half = tid >> 8;
        float v0 = sB[(half * 4 + 0) * LDS_STRIDE + t];
        float v1 = sB[(half * 4 + 1) * LDS_STRIDE + t];
        float v2 = sB[(half * 4 + 2) * LDS_STRIDE + t];
        float v3 = sB[(half * 4 + 3) * LDS_STRIDE + t];
        float4 o = {v0, v1, v2, v3};
        *(float4*)&fjt_cep[(b * 256 + t) * 64 + n0 + half * 4] = o;
    }
}

// ---------------- K3: edge logits + entropy, LDS-staged fjt, 4 i/block ----------------
// grid 512 = (b, ig); block 256 thr = 4 waves; wave s owns row i = ig*4+s, lane = j.
// fjt chunks [64 d][64 j] staged to LDS, reused by all 4 waves (4x L2 traffic cut).
__global__ __launch_bounds__(256) void k3_edges(
    const float* __restrict__ fi_dep, const float* __restrict__ fjt_dep,
    const float* __restrict__ fi_cep, const float* __restrict__ fjt_cep,
    const float* __restrict__ dep_w2, const float* __restrict__ dep_b2,
    const float* __restrict__ cep_w2, const float* __restrict__ cep_b2,
    float* __restrict__ Wd, float* __restrict__ Wc, float* __restrict__ entp)
{
    __shared__ float fjD_s[64 * 64];   // 16 KB chunk [d][j]
    __shared__ float fjC_s[64 * 64];   // 16 KB
    __shared__ float fiD_s[4][256];    // 4 KB
    __shared__ float fiC_s[4][256];    // 4 KB
    __shared__ float w2D_s[256];       // 1 KB
    __shared__ float w2C_s[256];       // 1 KB

    const int b   = blockIdx.x >> 4;
    const int ig  = blockIdx.x & 15;
    const int tid = threadIdx.x;
    const int s   = tid >> 6;          // wave id = local i
    const int j   = tid & 63;
    const int i   = ig * 4 + s;

    // stage fi rows (each wave stages its own row) + w2 vectors
    {
        int c = j * 4;
        *(float4*)&fiD_s[s][c] = *(const float4*)&fi_dep[(b * 64 + i) * 256 + c];
        *(float4*)&fiC_s[s][c] = *(const float4*)&fi_cep[(b * 64 + i) * 256 + c];
        if (tid < 64) {
            *(float4*)&w2D_s[tid * 4] = *(const float4*)&dep_w2[tid * 4];
        } else if (tid < 128) {
            int t = tid - 64;
            *(float4*)&w2C_s[t * 4] = *(const float4*)&cep_w2[t * 4];
        }
    }

    float accD0 = 0.0f, accD1 = 0.0f, accC0 = 0.0f, accC1 = 0.0f;

    for (int c0 = 0; c0 < 256; c0 += 64) {
        if (c0) __syncthreads();   // previous chunk's compute done before overwrite
        // stage fjt chunk: 4096 floats per array; 256 thr x 4 float4 each
        {
            const float4* sD = (const float4*)(fjt_dep + (b * 256 + c0) * 64);
            const float4* sC = (const float4*)(fjt_cep + (b * 256 + c0) * 64);
            #pragma unroll
            for (int kk = 0; kk < 4; ++kk) {
                ((float4*)fjD_s)[tid + kk * 256] = sD[tid + kk * 256];
                ((float4*)fjC_s)[tid + kk * 256] = sC[tid + kk * 256];
            }
        }
        __syncthreads();           // staging visible (covers fi/w2 on first iter)

        #pragma unroll 4
        for (int d = 0; d < 64; d += 2) {
            float fid0 = fiD_s[s][c0 + d];
            float fid1 = fiD_s[s][c0 + d + 1];
            float fic0 = fiC_s[s][c0 + d];
            float fic1 = fiC_s[s][c0 + d + 1];
            float fjd0 = fjD_s[(d + 0) * 64 + j];
            float fjd1 = fjD_s[(d + 1) * 64 + j];
            float fjc0 = fjC_s[(d + 0) * 64 + j];
            float fjc1 = fjC_s[(d + 1) * 64 + j];
            float wd0 = w2D_s[c0 + d], wd1 = w2D_s[c0 + d + 1];
            float wc0 = w2C_s[c0 + d], wc1 = w2C_s[c0 + d + 1];
            accD0 = fmaf(gelu_f(fid0 + fjd0), wd0, accD0);
            accD1 = fmaf(gelu_f(fid1 + fjd1), wd1, accD1);
            accC0 = fmaf(gelu_f(fic0 + fjc0), wc0, accC0);
            accC1 = fmaf(gelu_f(fic1 + fjc1), wc1, accC1);
        }
    }

    float lD = (accD0 + accD1) + dep_b2[0];
    float lC = (accC0 + accC1) + cep_b2[0];
    if (j == i) { lD = -1e9f; lC = -1e9f; }
    Wd[(b * 64 + i) * 64 + j] = lD;
    Wc[(b * 64 + i) * 64 + j] = lC;

    float p = sigmoid_f(lD);
    float e = -(p * logf(p + 1e-8f) + (1.0f - p) * logf(1.0f - p + 1e-8f));
    #pragma unroll
    for (int off = 32; off; off >>= 1) e += __shfl_down(e, off);
    if (j == 0) entp[b * 64 + i] = e;
}

// ---------------- K6: gate + combine + expm ----------------
__global__ __launch_bounds__(256) void k6_gate_expm(
    const float* __restrict__ Wd, const float* __restrict__ Wc,
    const float* __restrict__ entp,
    const float* __restrict__ gw1, const float* __restrict__ gb1,
    const float* __restrict__ gw2, const float* __restrict__ gb2,
    const int* __restrict__ n_samples,
    float* __restrict__ out, float* __restrict__ traces)
{
    __shared__ float Xs[64 * 68];
    __shared__ float Rs[64 * 68];
    __shared__ float sgate;
    __shared__ float sent;
    __shared__ int ssexp;

    const int b = blockIdx.x;
    const int tid = threadIdx.x;

    if (tid == 0) {
        float s = 0.0f;
        for (int c = 0; c < 64; ++c) s += entp[b * 64 + c];
        sent = s / 4096.0f;
    }
    __syncthreads();
    if (tid < 64) {
        float ns = fminf((float)n_samples[0] / 1000.0f, 1.0f);
        float ccf = 0.5f;
        float pre = ns * gw1[tid] + ccf * gw1[64 + tid] + sent * gw1[128 + tid] + gb1[tid];
        float hid = gelu_f(pre) * gw2[tid];
        #pragma unroll
        for (int off = 32; off; off >>= 1) hid += __shfl_down(hid, off);
        if (tid == 0) sgate = sigmoid_f(hid + gb2[0]);
    }
    __syncthreads();
    const float g = sgate;

    for (int idx = tid; idx < 4096; idx += 256) {
        float d = Wd[b * 4096 + idx];
        float c = Wc[b * 4096 + idx];
        float post = g * d + (1.0f - g) * c;
        float s = sigmoid_f(post);
        out[b * 4096 + idx] = s;
        int ii = idx >> 6, jj = idx & 63;
        Xs[ii * 68 + jj] = s * s;
    }
    __syncthreads();

    if (tid < 64) {
        float cs = 0.0f;
        for (int r = 0; r < 64; ++r) cs += Xs[r * 68 + tid];
        #pragma unroll
        for (int off = 32; off; off >>= 1) cs = fmaxf(cs, __shfl_down(cs, off));
        if (tid == 0) {
            int se = 0;
            if (cs > 0.5f) se = (int)ceilf(log2f(cs * 2.0f));
            if (se < 0) se = 0;
            if (se > 12) se = 12;
            ssexp = se;
        }
    }
    __syncthreads();
    const int sexp = ssexp;
    const float scale = ldexpf(1.0f, -sexp);
    for (int idx = tid; idx < 4096; idx += 256) {
        Xs[(idx >> 6) * 68 + (idx & 63)] *= scale;
    }
    __syncthreads();

    for (int idx = tid; idx < 4096; idx += 256) {
        int ii = idx >> 6, jj = idx & 63;
        Rs[ii * 68 + jj] = Xs[ii * 68 + jj] * (1.0f / 14.0f) + ((ii == jj) ? 1.0f : 0.0f);
    }
    __syncthreads();

    const int rq = tid >> 4, cq = tid & 15;
    const int r0 = rq * 4, c0 = cq * 4;

    for (int k = 13; k >= 1; --k) {
        float acc[4][4];
        #pragma unroll
        for (int i = 0; i < 4; ++i)
            #pragma unroll
            for (int j = 0; j < 4; ++j) acc[i][j] = 0.0f;
        for (int kb = 0; kb < 64; kb += 4) {
            float4 xa[4];
            #pragma unroll
            for (int i = 0; i < 4; ++i) xa[i] = *(const float4*)&Xs[(r0 + i) * 68 + kb];
            #pragma unroll
            for (int kk = 0; kk < 4; ++kk) {
                float4 rv = *(const float4*)&Rs[(kb + kk) * 68 + c0];
                float rj[4] = {rv.x, rv.y, rv.z, rv.w};
                #pragma unroll
                for (int i = 0; i < 4; ++i) {
                    float xv = f4c(xa[i], kk);
                    #pragma unroll
                    for (int j = 0; j < 4; ++j) acc[i][j] = fmaf(xv, rj[j], acc[i][j]);
                }
            }
        }
        __syncthreads();
        float invk = 1.0f / (float)k;
        #pragma unroll
        for (int i = 0; i < 4; ++i)
            #pragma unroll
            for (int j = 0; j < 4; ++j)
                Rs[(r0 + i) * 68 + c0 + j] = acc[i][j] * invk + (((r0 + i) == (c0 + j)) ? 1.0f : 0.0f);
        __syncthreads();
    }

    for (int sq = 0; sq < sexp; ++sq) {
        double acc[4][4];
        #pragma unroll
        for (int i = 0; i < 4; ++i)
            #pragma unroll
            for (int j = 0; j < 4; ++j) acc[i][j] = 0.0;
        for (int kb = 0; kb < 64; kb += 4) {
            float4 xa[4];
            #pragma unroll
            for (int i = 0; i < 4; ++i) xa[i] = *(const float4*)&Rs[(r0 + i) * 68 + kb];
            #pragma unroll
            for (int kk = 0; kk < 4; ++kk) {
                float4 rv = *(const float4*)&Rs[(kb + kk) * 68 + c0];
                double rj[4] = {(double)rv.x, (double)rv.y, (double)rv.z, (double)rv.w};
                #pragma unroll
                for (int i = 0; i < 4; ++i) {
                    double xv = (double)f4c(xa[i], kk);
                    #pragma unroll
                    for (int j = 0; j < 4; ++j) acc[i][j] = fma(xv, rj[j], acc[i][j]);
                }
            }
        }
        __syncthreads();
        #pragma unroll
        for (int i = 0; i < 4; ++i)
            #pragma unroll
            for (int j = 0; j < 4; ++j)
                Rs[(r0 + i) * 68 + c0 + j] = (float)acc[i][j];
        __syncthreads();
    }

    if (tid == 0) {
        double tr = 0.0;
        for (int i = 0; i < 64; ++i) tr += (double)Rs[i * 68 + i];
        traces[b] = (float)tr;
    }
}

// ---------------- K7: acyc ----------------
__global__ void k7_acyc(const float* __restrict__ traces, float* __restrict__ out)
{
    if (threadIdx.x == 0 && blockIdx.x == 0) {
        double s = 0.0;
        for (int b = 0; b < 32; ++b) s += (double)traces[b];
        out[131072] = (float)(s / 32.0 - 64.0);
    }
}

extern "C" void kernel_launch(void* const* d_in, const int* in_sizes, int n_in,
                              void* d_out, int out_size, void* d_ws, size_t ws_size,
                              hipStream_t stream)
{
    (void)in_sizes; (void)n_in; (void)out_size; (void)ws_size;

    const float* ds     = (const float*)d_in[0];
    const float* ve     = (const float*)d_in[1];
    const float* cc     = (const float*)d_in[2];
    const float* dge_w1 = (const float*)d_in[3];
    const float* dge_b1 = (const float*)d_in[4];
    const float* dge_w2 = (const float*)d_in[5];
    const float* dge_b2 = (const float*)d_in[6];
    const float* cge_w1 = (const float*)d_in[7];
    const float* cge_b1 = (const float*)d_in[8];
    const float* cge_w2 = (const float*)d_in[9];
    const float* cge_b2 = (const float*)d_in[10];
    const float* dep_w1 = (const float*)d_in[11];
    const float* dep_b1 = (const float*)d_in[12];
    const float* dep_w2 = (const float*)d_in[13];
    const float* dep_b2 = (const float*)d_in[14];
    const float* cep_w1 = (const float*)d_in[15];
    const float* cep_b1 = (const float*)d_in[16];
    const float* cep_w2 = (const float*)d_in[17];
    const float* cep_b2 = (const float*)d_in[18];
    const float* gw1    = (const float*)d_in[19];
    const float* gb1    = (const float*)d_in[20];
    const float* gw2    = (const float*)d_in[21];
    const float* gb2    = (const float*)d_in[22];
    const int*   nsamp  = (const int*)d_in[23];

    float* ws = (float*)d_ws;
    float* ctxproj = ws;                       // 6*32*256   = 49152
    float* fi_dep  = ctxproj + 49152;          // 32*64*256  = 524288
    float* fjt_dep = fi_dep + 524288;          // 524288
    float* fi_cep  = fjt_dep + 524288;         // 524288
    float* fjt_cep = fi_cep + 524288;          // 524288
    float* Wd      = fjt_cep + 524288;         // 131072
    float* Wc      = Wd + 131072;              // 131072
    float* entp    = Wc + 131072;              // 2048
    float* traces  = entp + 2048;              // 32

    float* outp = (float*)d_out;

    k0_ctx<<<dim3(32, 6), 256, 0, stream>>>(ds, cc, dge_w1, dge_b1, cge_w1, cge_b1,
                                            dep_w1, dep_b1, cep_w1, cep_b1, ctxproj);
    k1_encode<<<256, 512, 0, stream>>>(ve, dge_w1, dge_w2, dge_b2,
                                       cge_w1, cge_w2, cge_b2,
                                       dep_w1, cep_w1, ctxproj,
                                       fi_dep, fjt_dep, fi_cep, fjt_cep);
    k3_edges<<<512, 256, 0, stream>>>(fi_dep, fjt_dep, fi_cep, fjt_cep,
                                      dep_w2, dep_b2, cep_w2, cep_b2,
                                      Wd, Wc, entp);
    k6_gate_expm<<<32, 256, 0, stream>>>(Wd, Wc, entp, gw1, gb1, gw2, gb2,
                                         nsamp, outp, traces);
    k7_acyc<<<1, 64, 0, stream>>>(traces, outp);
}

// Round 5
// 136.647 us; speedup vs baseline: 1.6581x; 1.1151x over previous
//
#include <hip/hip_runtime.h>
#include <hip/hip_bf16.h>

// GraphPosteriorHead: B=32, N=64, D=256
// Pipeline:
//  K0: ctx projections (6x (32,256))       -> ws
//  K1: fused encoders + fi/fj projections  -> fi_dep, fjt_dep, fi_cep, fjt_cep
//  K3: edge logits + entropy; LDS-staged fjt chunks, 4 i-rows/block reuse
//  K6: gate + combine + W_posterior + expm(trace) per batch -> out, traces
//      (Paterson-Stockmeyer Taylor-13: 6 fp32 mm + sexp fp64 squarings,
//       ping-pong LDS buffers, 1 barrier per mm)
//  K7: acyc reduction -> out[131072]

#define LDS_STRIDE 260   // 256 + 4 pad
#define ES 68            // expm LDS row stride (64+4, keeps float4 align, kills conflicts)

__device__ __forceinline__ float gelu_f(float x) {
    return 0.5f * x * (1.0f + erff(x * 0.70710678118654752440f));
}
__device__ __forceinline__ float sigmoid_f(float x) {
    return 1.0f / (1.0f + expf(-x));
}
__device__ __forceinline__ float f4c(const float4& v, int k) {
    return k == 0 ? v.x : k == 1 ? v.y : k == 2 ? v.z : v.w;
}
__device__ __forceinline__ float4 ld4(const float* __restrict__ buf, int r, int c) {
    return *(const float4*)&buf[r * ES + c];
}

// ---------------- K0: context projections ----------------
__global__ __launch_bounds__(256) void k0_ctx(
    const float* __restrict__ ds, const float* __restrict__ cc,
    const float* __restrict__ dge_w1, const float* __restrict__ dge_b1,
    const float* __restrict__ cge_w1, const float* __restrict__ cge_b1,
    const float* __restrict__ dep_w1, const float* __restrict__ dep_b1,
    const float* __restrict__ cep_w1, const float* __restrict__ cep_b1,
    float* __restrict__ ctxproj)
{
    const int b = blockIdx.x;
    const int which = blockIdx.y;
    const float* ctx; const float* W; const float* bias;
    switch (which) {
        case 0:  ctx = ds; W = dge_w1 + 256 * 256; bias = dge_b1; break;
        case 1:  ctx = cc; W = cge_w1 + 256 * 256; bias = cge_b1; break;
        case 2:  ctx = ds; W = dep_w1 + 256 * 256; bias = dep_b1; break;
        case 3:  ctx = ds; W = dep_w1 + 768 * 256; bias = nullptr; break;
        case 4:  ctx = cc; W = cep_w1 + 256 * 256; bias = cep_b1; break;
        default: ctx = cc; W = cep_w1 + 768 * 256; bias = nullptr; break;
    }
    __shared__ float sctx[256];
    const int tid = threadIdx.x;
    sctx[tid] = ctx[b * 256 + tid];
    __syncthreads();
    float acc = 0.0f;
    #pragma unroll 2
    for (int k = 0; k < 256; k += 4) {
        float4 c4 = *(const float4*)&sctx[k];
        acc = fmaf(c4.x, W[(k + 0) * 256 + tid], acc);
        acc = fmaf(c4.y, W[(k + 1) * 256 + tid], acc);
        acc = fmaf(c4.z, W[(k + 2) * 256 + tid], acc);
        acc = fmaf(c4.w, W[(k + 3) * 256 + tid], acc);
    }
    if (bias) acc += bias[tid];
    ctxproj[(which * 32 + b) * 256 + tid] = acc;
}

// ---------------- K1: fused encoders, k-split across 8 waves ----------------
__device__ __forceinline__ void gemm_ks(const float* __restrict__ src,  // LDS [8][LDS_STRIDE]
                                        const float* __restrict__ W,    // global [256][256]
                                        int ks0, int t0, float acc[8][4])
{
    #pragma unroll
    for (int r = 0; r < 8; ++r)
        #pragma unroll
        for (int c = 0; c < 4; ++c) acc[r][c] = 0.0f;
    #pragma unroll 2
    for (int k = ks0; k < ks0 + 32; k += 4) {
        float4 wv0 = *(const float4*)&W[(k + 0) * 256 + t0];
        float4 wv1 = *(const float4*)&W[(k + 1) * 256 + t0];
        float4 wv2 = *(const float4*)&W[(k + 2) * 256 + t0];
        float4 wv3 = *(const float4*)&W[(k + 3) * 256 + t0];
        float4 a[8];
        #pragma unroll
        for (int r = 0; r < 8; ++r) a[r] = *(const float4*)&src[r * LDS_STRIDE + k];
        float4 wvs[4] = {wv0, wv1, wv2, wv3};
        #pragma unroll
        for (int kk = 0; kk < 4; ++kk) {
            float4 wv = wvs[kk];
            #pragma unroll
            for (int r = 0; r < 8; ++r) {
                float av = f4c(a[r], kk);
                acc[r][0] = fmaf(av, wv.x, acc[r][0]);
                acc[r][1] = fmaf(av, wv.y, acc[r][1]);
                acc[r][2] = fmaf(av, wv.z, acc[r][2]);
                acc[r][3] = fmaf(av, wv.w, acc[r][3]);
            }
        }
    }
}

__device__ __forceinline__ void write_part(float* __restrict__ part, int w, int t0,
                                           const float acc[8][4])
{
    #pragma unroll
    for (int r = 0; r < 8; ++r) {
        float4 o = {acc[r][0], acc[r][1], acc[r][2], acc[r][3]};
        *(float4*)&part[(w * 8 + r) * 256 + t0] = o;
    }
}

__device__ __forceinline__ float4 reduce_part(const float* __restrict__ part, int r, int t0)
{
    float4 s = {0.0f, 0.0f, 0.0f, 0.0f};
    #pragma unroll
    for (int w = 0; w < 8; ++w) {
        float4 v = *(const float4*)&part[(w * 8 + r) * 256 + t0];
        s.x += v.x; s.y += v.y; s.z += v.z; s.w += v.w;
    }
    return s;
}

__global__ __launch_bounds__(512) void k1_encode(
    const float* __restrict__ ve_g,
    const float* __restrict__ dge_w1, const float* __restrict__ dge_w2, const float* __restrict__ dge_b2,
    const float* __restrict__ cge_w1, const float* __restrict__ cge_w2, const float* __restrict__ cge_b2,
    const float* __restrict__ dep_w1, const float* __restrict__ cep_w1,
    const float* __restrict__ ctxproj,
    float* __restrict__ fi_dep, float* __restrict__ fjt_dep,
    float* __restrict__ fi_cep, float* __restrict__ fjt_cep)
{
    __shared__ float sve[8 * LDS_STRIDE];
    __shared__ float sA[8 * LDS_STRIDE];
    __shared__ float sB[8 * LDS_STRIDE];
    __shared__ float part[8 * 8 * 256];   // 64 KB partials

    const int tid = threadIdx.x;
    const int b = blockIdx.x >> 3;
    const int chunk = blockIdx.x & 7;
    const int n0 = chunk * 8;

    const int w  = tid >> 6;          // wave id 0..7
    const int t0 = (tid & 63) * 4;    // 4-col slice
    const int ks0 = w * 32;           // k-slice

    {
        int idx = tid * 4;
        int r = idx >> 8, k = idx & 255;
        *(float4*)&sve[r * LDS_STRIDE + k] = *(const float4*)&ve_g[(b * 64 + n0) * 256 + idx];
    }
    __syncthreads();

    float acc[8][4];

    // ---- 1. dge stage1: sve -> sA
    gemm_ks(sve, dge_w1, ks0, t0, acc);
    write_part(part, w, t0, acc);
    __syncthreads();
    {
        float4 s = reduce_part(part, w, t0);
        float4 cp = *(const float4*)&ctxproj[(0 * 32 + b) * 256 + t0];
        float4 o = {gelu_f(s.x + cp.x), gelu_f(s.y + cp.y), gelu_f(s.z + cp.z), gelu_f(s.w + cp.w)};
        *(float4*)&sA[w * LDS_STRIDE + t0] = o;
    }
    __syncthreads();

    // ---- 2. dge stage2: sA -> sB (var_data)
    gemm_ks(sA, dge_w2, ks0, t0, acc);
    write_part(part, w, t0, acc);
    __syncthreads();
    {
        float4 s = reduce_part(part, w, t0);
        float4 bv = *(const float4*)&dge_b2[t0];
        float4 o = {gelu_f(s.x + bv.x), gelu_f(s.y + bv.y), gelu_f(s.z + bv.z), gelu_f(s.w + bv.w)};
        *(float4*)&sB[w * LDS_STRIDE + t0] = o;
    }
    __syncthreads();

    // ---- 3. dep fi: sB -> global
    gemm_ks(sB, dep_w1, ks0, t0, acc);
    write_part(part, w, t0, acc);
    __syncthreads();
    {
        float4 s = reduce_part(part, w, t0);
        float4 cp = *(const float4*)&ctxproj[(2 * 32 + b) * 256 + t0];
        float4 o = {s.x + cp.x, s.y + cp.y, s.z + cp.z, s.w + cp.w};
        *(float4*)&fi_dep[(b * 64 + n0 + w) * 256 + t0] = o;
    }
    __syncthreads();

    // ---- 4. dep fj: sB -> sA, then transpose to fjt_dep
    gemm_ks(sB, dep_w1 + 512 * 256, ks0, t0, acc);
    write_part(part, w, t0, acc);
    __syncthreads();
    {
        float4 s = reduce_part(part, w, t0);
        float4 cp = *(const float4*)&ctxproj[(3 * 32 + b) * 256 + t0];
        float4 o = {s.x + cp.x, s.y + cp.y, s.z + cp.z, s.w + cp.w};
        *(float4*)&sA[w * LDS_STRIDE + t0] = o;
    }
    __syncthreads();
    {
        int t = tid & 255, half = tid >> 8;
        float v0 = sA[(half * 4 + 0) * LDS_STRIDE + t];
        float v1 = sA[(half * 4 + 1) * LDS_STRIDE + t];
        float v2 = sA[(half * 4 + 2) * LDS_STRIDE + t];
        float v3 = sA[(half * 4 + 3) * LDS_STRIDE + t];
        float4 o = {v0, v1, v2, v3};
        *(float4*)&fjt_dep[(b * 256 + t) * 64 + n0 + half * 4] = o;
    }

    // ---- 5. cge stage1: sve -> sB
    gemm_ks(sve, cge_w1, ks0, t0, acc);
    write_part(part, w, t0, acc);
    __syncthreads();
    {
        float4 s = reduce_part(part, w, t0);
        float4 cp = *(const float4*)&ctxproj[(1 * 32 + b) * 256 + t0];
        float4 o = {gelu_f(s.x + cp.x), gelu_f(s.y + cp.y), gelu_f(s.z + cp.z), gelu_f(s.w + cp.w)};
        *(float4*)&sB[w * LDS_STRIDE + t0] = o;
    }
    __syncthreads();

    // ---- 6. cge stage2: sB -> sA (var_claim)
    gemm_ks(sB, cge_w2, ks0, t0, acc);
    write_part(part, w, t0, acc);
    __syncthreads();
    {
        float4 s = reduce_part(part, w, t0);
        float4 bv = *(const float4*)&cge_b2[t0];
        float4 o = {gelu_f(s.x + bv.x), gelu_f(s.y + bv.y), gelu_f(s.z + bv.z), gelu_f(s.w + bv.w)};
        *(float4*)&sA[w * LDS_STRIDE + t0] = o;
    }
    __syncthreads();

    // ---- 7. cep fi: sA -> global
    gemm_ks(sA, cep_w1, ks0, t0, acc);
    write_part(part, w, t0, acc);
    __syncthreads();
    {
        float4 s = reduce_part(part, w, t0);
        float4 cp = *(const float4*)&ctxproj[(4 * 32 + b) * 256 + t0];
        float4 o = {s.x + cp.x, s.y + cp.y, s.z + cp.z, s.w + cp.w};
        *(float4*)&fi_cep[(b * 64 + n0 + w) * 256 + t0] = o;
    }
    __syncthreads();

    // ---- 8. cep fj: sA -> sB, then transpose to fjt_cep
    gemm_ks(sA, cep_w1 + 512 * 256, ks0, t0, acc);
    write_part(part, w, t0, acc);
    __syncthreads();
    {
        float4 s = reduce_part(part, w, t0);
        float4 cp = *(const float4*)&ctxproj[(5 * 32 + b) * 256 + t0];
        float4 o = {s.x + cp.x, s.y + cp.y, s.z + cp.z, s.w + cp.w};
        *(float4*)&sB[w * LDS_STRIDE + t0] = o;
    }
    __syncthreads();
    {
        int t = tid & 255, half = tid >> 8;
        float v0 = sB[(half * 4 + 0) * LDS_STRIDE + t];
        float v1 = sB[(half * 4 + 1) * LDS_STRIDE + t];
        float v2 = sB[(half * 4 + 2) * LDS_STRIDE + t];
        float v3 = sB[(half * 4 + 3) * LDS_STRIDE + t];
        float4 o = {v0, v1, v2, v3};
        *(float4*)&fjt_cep[(b * 256 + t) * 64 + n0 + half * 4] = o;
    }
}

// ---------------- K3: edge logits + entropy, LDS-staged fjt, 4 i/block ----------------
__global__ __launch_bounds__(256) void k3_edges(
    const float* __restrict__ fi_dep, const float* __restrict__ fjt_dep,
    const float* __restrict__ fi_cep, const float* __restrict__ fjt_cep,
    const float* __restrict__ dep_w2, const float* __restrict__ dep_b2,
    const float* __restrict__ cep_w2, const float* __restrict__ cep_b2,
    float* __restrict__ Wd, float* __restrict__ Wc, float* __restrict__ entp)
{
    __shared__ float fjD_s[64 * 64];
    __shared__ float fjC_s[64 * 64];
    __shared__ float fiD_s[4][256];
    __shared__ float fiC_s[4][256];
    __shared__ float w2D_s[256];
    __shared__ float w2C_s[256];

    const int b   = blockIdx.x >> 4;
    const int ig  = blockIdx.x & 15;
    const int tid = threadIdx.x;
    const int s   = tid >> 6;
    const int j   = tid & 63;
    const int i   = ig * 4 + s;

    {
        int c = j * 4;
        *(float4*)&fiD_s[s][c] = *(const float4*)&fi_dep[(b * 64 + i) * 256 + c];
        *(float4*)&fiC_s[s][c] = *(const float4*)&fi_cep[(b * 64 + i) * 256 + c];
        if (tid < 64) {
            *(float4*)&w2D_s[tid * 4] = *(const float4*)&dep_w2[tid * 4];
        } else if (tid < 128) {
            int t = tid - 64;
            *(float4*)&w2C_s[t * 4] = *(const float4*)&cep_w2[t * 4];
        }
    }

    float accD0 = 0.0f, accD1 = 0.0f, accC0 = 0.0f, accC1 = 0.0f;

    for (int c0 = 0; c0 < 256; c0 += 64) {
        if (c0) __syncthreads();
        {
            const float4* sD = (const float4*)(fjt_dep + (b * 256 + c0) * 64);
            const float4* sC = (const float4*)(fjt_cep + (b * 256 + c0) * 64);
            #pragma unroll
            for (int kk = 0; kk < 4; ++kk) {
                ((float4*)fjD_s)[tid + kk * 256] = sD[tid + kk * 256];
                ((float4*)fjC_s)[tid + kk * 256] = sC[tid + kk * 256];
            }
        }
        __syncthreads();

        #pragma unroll 4
        for (int d = 0; d < 64; d += 2) {
            float fid0 = fiD_s[s][c0 + d];
            float fid1 = fiD_s[s][c0 + d + 1];
            float fic0 = fiC_s[s][c0 + d];
            float fic1 = fiC_s[s][c0 + d + 1];
            float fjd0 = fjD_s[(d + 0) * 64 + j];
            float fjd1 = fjD_s[(d + 1) * 64 + j];
            float fjc0 = fjC_s[(d + 0) * 64 + j];
            float fjc1 = fjC_s[(d + 1) * 64 + j];
            float wd0 = w2D_s[c0 + d], wd1 = w2D_s[c0 + d + 1];
            float wc0 = w2C_s[c0 + d], wc1 = w2C_s[c0 + d + 1];
            accD0 = fmaf(gelu_f(fid0 + fjd0), wd0, accD0);
            accD1 = fmaf(gelu_f(fid1 + fjd1), wd1, accD1);
            accC0 = fmaf(gelu_f(fic0 + fjc0), wc0, accC0);
            accC1 = fmaf(gelu_f(fic1 + fjc1), wc1, accC1);
        }
    }

    float lD = (accD0 + accD1) + dep_b2[0];
    float lC = (accC0 + accC1) + cep_b2[0];
    if (j == i) { lD = -1e9f; lC = -1e9f; }
    Wd[(b * 64 + i) * 64 + j] = lD;
    Wc[(b * 64 + i) * 64 + j] = lC;

    float p = sigmoid_f(lD);
    float e = -(p * logf(p + 1e-8f) + (1.0f - p) * logf(1.0f - p + 1e-8f));
    #pragma unroll
    for (int off = 32; off; off >>= 1) e += __shfl_down(e, off);
    if (j == 0) entp[b * 64 + i] = e;
}

// ---------------- K6: gate + combine + expm (Paterson-Stockmeyer) ----------------
// Taylor-13 of exp(A), A scaled so ||A||_1 <= 1:
//   Y = X^3; p = (((B4*Y + B3)*Y + B2)*Y + B1)*Y + B0,  B_i = a_i I + b_i X + c_i X2
// 6 fp32 matmuls + sexp fp64 squarings; ping-pong buffers, 1 barrier per mm.
__device__ __forceinline__ void mm64f(const float* __restrict__ A, const float* __restrict__ B,
                                      int r0, int c0, float acc[4][4])
{
    #pragma unroll
    for (int i = 0; i < 4; ++i)
        #pragma unroll
        for (int j = 0; j < 4; ++j) acc[i][j] = 0.0f;
    for (int kb = 0; kb < 64; kb += 4) {
        float4 xa[4];
        #pragma unroll
        for (int i = 0; i < 4; ++i) xa[i] = ld4(A, r0 + i, kb);
        #pragma unroll
        for (int kk = 0; kk < 4; ++kk) {
            float4 rv = ld4(B, kb + kk, c0);
            float rj[4] = {rv.x, rv.y, rv.z, rv.w};
            #pragma unroll
            for (int i = 0; i < 4; ++i) {
                float xv = f4c(xa[i], kk);
                #pragma unroll
                for (int j = 0; j < 4; ++j) acc[i][j] = fmaf(xv, rj[j], acc[i][j]);
            }
        }
    }
}

__device__ __forceinline__ void mm64d(const float* __restrict__ A, const float* __restrict__ B,
                                      int r0, int c0, double acc[4][4])
{
    #pragma unroll
    for (int i = 0; i < 4; ++i)
        #pragma unroll
        for (int j = 0; j < 4; ++j) acc[i][j] = 0.0;
    for (int kb = 0; kb < 64; kb += 4) {
        float4 xa[4];
        #pragma unroll
        for (int i = 0; i < 4; ++i) xa[i] = ld4(A, r0 + i, kb);
        #pragma unroll
        for (int kk = 0; kk < 4; ++kk) {
            float4 rv = ld4(B, kb + kk, c0);
            double rj[4] = {(double)rv.x, (double)rv.y, (double)rv.z, (double)rv.w};
            #pragma unroll
            for (int i = 0; i < 4; ++i) {
                double xv = (double)f4c(xa[i], kk);
                #pragma unroll
                for (int j = 0; j < 4; ++j) acc[i][j] = fma(xv, rj[j], acc[i][j]);
            }
        }
    }
}

__global__ __launch_bounds__(256) void k6_gate_expm(
    const float* __restrict__ Wd, const float* __restrict__ Wc,
    const float* __restrict__ entp,
    const float* __restrict__ gw1, const float* __restrict__ gb1,
    const float* __restrict__ gw2, const float* __restrict__ gb2,
    const int* __restrict__ n_samples,
    float* __restrict__ out, float* __restrict__ traces)
{
    __shared__ float Xs [64 * ES];
    __shared__ float X2s[64 * ES];
    __shared__ float X3s[64 * ES];
    __shared__ float Ra [64 * ES];
    __shared__ float Rb [64 * ES];
    __shared__ float sgate;
    __shared__ float sent;
    __shared__ int ssexp;

    const int b = blockIdx.x;
    const int tid = threadIdx.x;

    // 1/k! coefficients
    const float C2 = 0.5f, C3 = 1.0f/6.0f, C4 = 1.0f/24.0f, C5 = 1.0f/120.0f;
    const float C6 = 1.0f/720.0f, C7 = 1.0f/5040.0f, C8 = 1.0f/40320.0f;
    const float C9 = 1.0f/362880.0f, C10 = 1.0f/3628800.0f, C11 = 1.0f/39916800.0f;
    const float C12 = 1.0f/479001600.0f, C13 = 1.0f/6227020800.0f;

    if (tid == 0) {
        float s = 0.0f;
        for (int c = 0; c < 64; ++c) s += entp[b * 64 + c];
        sent = s / 4096.0f;
    }
    __syncthreads();
    if (tid < 64) {
        float ns = fminf((float)n_samples[0] / 1000.0f, 1.0f);
        float ccf = 0.5f;
        float pre = ns * gw1[tid] + ccf * gw1[64 + tid] + sent * gw1[128 + tid] + gb1[tid];
        float hid = gelu_f(pre) * gw2[tid];
        #pragma unroll
        for (int off = 32; off; off >>= 1) hid += __shfl_down(hid, off);
        if (tid == 0) sgate = sigmoid_f(hid + gb2[0]);
    }
    __syncthreads();
    const float g = sgate;

    // combine + write W_posterior + build X = Wsig^2
    for (int idx = tid; idx < 4096; idx += 256) {
        float d = Wd[b * 4096 + idx];
        float c = Wc[b * 4096 + idx];
        float post = g * d + (1.0f - g) * c;
        float sg = sigmoid_f(post);
        out[b * 4096 + idx] = sg;
        Xs[(idx >> 6) * ES + (idx & 63)] = sg * sg;
    }
    __syncthreads();

    // 1-norm -> scaling exponent (threshold 1.0)
    if (tid < 64) {
        float cs = 0.0f;
        for (int r = 0; r < 64; ++r) cs += Xs[r * ES + tid];
        #pragma unroll
        for (int off = 32; off; off >>= 1) cs = fmaxf(cs, __shfl_down(cs, off));
        if (tid == 0) {
            int se = 0;
            if (cs > 1.0f) se = (int)ceilf(log2f(cs));
            if (se < 0) se = 0;
            if (se > 12) se = 12;
            ssexp = se;
        }
    }
    __syncthreads();
    const int sexp = ssexp;
    const float scale = ldexpf(1.0f, -sexp);
    for (int idx = tid; idx < 4096; idx += 256) {
        Xs[(idx >> 6) * ES + (idx & 63)] *= scale;
    }
    __syncthreads();

    const int rq = tid >> 4, cq = tid & 15;
    const int r0 = rq * 4, c0 = cq * 4;
    float acc[4][4];

    // mm1: X2 = X*X
    mm64f(Xs, Xs, r0, c0, acc);
    #pragma unroll
    for (int i = 0; i < 4; ++i) {
        float4 o = {acc[i][0], acc[i][1], acc[i][2], acc[i][3]};
        *(float4*)&X2s[(r0 + i) * ES + c0] = o;
    }
    __syncthreads();

    // mm2: X3 = X2*X
    mm64f(X2s, Xs, r0, c0, acc);
    #pragma unroll
    for (int i = 0; i < 4; ++i) {
        float4 o = {acc[i][0], acc[i][1], acc[i][2], acc[i][3]};
        *(float4*)&X3s[(r0 + i) * ES + c0] = o;
    }
    __syncthreads();

    // mm3: Ra = B4*Y + B3 = C13*(X*X3) + C12*X3 + (C9 I + C10 X + C11 X2)
    mm64f(Xs, X3s, r0, c0, acc);
    #pragma unroll
    for (int i = 0; i < 4; ++i) {
        float4 xv = ld4(Xs, r0 + i, c0);
        float4 x2 = ld4(X2s, r0 + i, c0);
        float4 x3 = ld4(X3s, r0 + i, c0);
        float o[4];
        #pragma unroll
        for (int j = 0; j < 4; ++j) {
            o[j] = C13 * acc[i][j] + C12 * f4c(x3, j) + C10 * f4c(xv, j) + C11 * f4c(x2, j)
                 + ((r0 + i) == (c0 + j) ? C9 : 0.0f);
        }
        float4 ov = {o[0], o[1], o[2], o[3]};
        *(float4*)&Ra[(r0 + i) * ES + c0] = ov;
    }
    __syncthreads();

    // mm4: Rb = Ra*Y + B2 (B2 = C6 I + C7 X + C8 X2)
    mm64f(Ra, X3s, r0, c0, acc);
    #pragma unroll
    for (int i = 0; i < 4; ++i) {
        float4 xv = ld4(Xs, r0 + i, c0);
        float4 x2 = ld4(X2s, r0 + i, c0);
        float o[4];
        #pragma unroll
        for (int j = 0; j < 4; ++j) {
            o[j] = acc[i][j] + C7 * f4c(xv, j) + C8 * f4c(x2, j)
                 + ((r0 + i) == (c0 + j) ? C6 : 0.0f);
        }
        float4 ov = {o[0], o[1], o[2], o[3]};
        *(float4*)&Rb[(r0 + i) * ES + c0] = ov;
    }
    __syncthreads();

    // mm5: Ra = Rb*Y + B1 (B1 = C3 I + C4 X + C5 X2)
    mm64f(Rb, X3s, r0, c0, acc);
    #pragma unroll
    for (int i = 0; i < 4; ++i) {
        float4 xv = ld4(Xs, r0 + i, c0);
        float4 x2 = ld4(X2s, r0 + i, c0);
        float o[4];
        #pragma unroll
        for (int j = 0; j < 4; ++j) {
            o[j] = acc[i][j] + C4 * f4c(xv, j) + C5 * f4c(x2, j)
                 + ((r0 + i) == (c0 + j) ? C3 : 0.0f);
        }
        float4 ov = {o[0], o[1], o[2], o[3]};
        *(float4*)&Ra[(r0 + i) * ES + c0] = ov;
    }
    __syncthreads();

    // mm6: Rb = Ra*Y + B0 (B0 = I + X + C2 X2)
    mm64f(Ra, X3s, r0, c0, acc);
    #pragma unroll
    for (int i = 0; i < 4; ++i) {
        float4 xv = ld4(Xs, r0 + i, c0);
        float4 x2 = ld4(X2s, r0 + i, c0);
        float o[4];
        #pragma unroll
        for (int j = 0; j < 4; ++j) {
            o[j] = acc[i][j] + f4c(xv, j) + C2 * f4c(x2, j)
                 + ((r0 + i) == (c0 + j) ? 1.0f : 0.0f);
        }
        float4 ov = {o[0], o[1], o[2], o[3]};
        *(float4*)&Rb[(r0 + i) * ES + c0] = ov;
    }
    __syncthreads();

    // squarings (fp64 accumulation), ping-pong Rb <-> Ra
    float* cur = Rb;
    float* oth = Ra;
    for (int sq = 0; sq < sexp; ++sq) {
        double dacc[4][4];
        mm64d(cur, cur, r0, c0, dacc);
        #pragma unroll
        for (int i = 0; i < 4; ++i) {
            float4 o = {(float)dacc[i][0], (float)dacc[i][1], (float)dacc[i][2], (float)dacc[i][3]};
            *(float4*)&oth[(r0 + i) * ES + c0] = o;
        }
        __syncthreads();
        float* t = cur; cur = oth; oth = t;
    }

    if (tid == 0) {
        double tr = 0.0;
        for (int i = 0; i < 64; ++i) tr += (double)cur[i * ES + i];
        traces[b] = (float)tr;
    }
}

// ---------------- K7: acyc ----------------
__global__ void k7_acyc(const float* __restrict__ traces, float* __restrict__ out)
{
    if (threadIdx.x == 0 && blockIdx.x == 0) {
        double s = 0.0;
        for (int b = 0; b < 32; ++b) s += (double)traces[b];
        out[131072] = (float)(s / 32.0 - 64.0);
    }
}

extern "C" void kernel_launch(void* const* d_in, const int* in_sizes, int n_in,
                              void* d_out, int out_size, void* d_ws, size_t ws_size,
                              hipStream_t stream)
{
    (void)in_sizes; (void)n_in; (void)out_size; (void)ws_size;

    const float* ds     = (const float*)d_in[0];
    const float* ve     = (const float*)d_in[1];
    const float* cc     = (const float*)d_in[2];
    const float* dge_w1 = (const float*)d_in[3];
    const float* dge_b1 = (const float*)d_in[4];
    const float* dge_w2 = (const float*)d_in[5];
    const float* dge_b2 = (const float*)d_in[6];
    const float* cge_w1 = (const float*)d_in[7];
    const float* cge_b1 = (const float*)d_in[8];
    const float* cge_w2 = (const float*)d_in[9];
    const float* cge_b2 = (const float*)d_in[10];
    const float* dep_w1 = (const float*)d_in[11];
    const float* dep_b1 = (const float*)d_in[12];
    const float* dep_w2 = (const float*)d_in[13];
    const float* dep_b2 = (const float*)d_in[14];
    const float* cep_w1 = (const float*)d_in[15];
    const float* cep_b1 = (const float*)d_in[16];
    const float* cep_w2 = (const float*)d_in[17];
    const float* cep_b2 = (const float*)d_in[18];
    const float* gw1    = (const float*)d_in[19];
    const float* gb1    = (const float*)d_in[20];
    const float* gw2    = (const float*)d_in[21];
    const float* gb2    = (const float*)d_in[22];
    const int*   nsamp  = (const int*)d_in[23];

    float* ws = (float*)d_ws;
    float* ctxproj = ws;                       // 6*32*256   = 49152
    float* fi_dep  = ctxproj + 49152;          // 32*64*256  = 524288
    float* fjt_dep = fi_dep + 524288;          // 524288
    float* fi_cep  = fjt_dep + 524288;         // 524288
    float* fjt_cep = fi_cep + 524288;          // 524288
    float* Wd      = fjt_cep + 524288;         // 131072
    float* Wc      = Wd + 131072;              // 131072
    float* entp    = Wc + 131072;              // 2048
    float* traces  = entp + 2048;              // 32

    float* outp = (float*)d_out;

    k0_ctx<<<dim3(32, 6), 256, 0, stream>>>(ds, cc, dge_w1, dge_b1, cge_w1, cge_b1,
                                            dep_w1, dep_b1, cep_w1, cep_b1, ctxproj);
    k1_encode<<<256, 512, 0, stream>>>(ve, dge_w1, dge_w2, dge_b2,
                                       cge_w1, cge_w2, cge_b2,
                                       dep_w1, cep_w1, ctxproj,
                                       fi_dep, fjt_dep, fi_cep, fjt_cep);
    k3_edges<<<512, 256, 0, stream>>>(fi_dep, fjt_dep, fi_cep, fjt_cep,
                                      dep_w2, dep_b2, cep_w2, cep_b2,
                                      Wd, Wc, entp);
    k6_gate_expm<<<32, 256, 0, stream>>>(Wd, Wc, entp, gw1, gb1, gw2, gb2,
                                         nsamp, outp, traces);
    k7_acyc<<<1, 64, 0, stream>>>(traces, outp);
}